// Round 3
// baseline (2200.375 us; speedup 1.0000x reference)
//
#include <hip/hip_runtime.h>
#include <math.h>

typedef unsigned long long ull;

#define NN1 50000
#define EE  600000
#define KK1 25000
#define KK2 12500

#define CDIV(a,b) (((a)+(b)-1)/(b))

__device__ __forceinline__ ull encd(double d){
  ull u = (ull)__double_as_longlong(d);
  return (u & 0x8000000000000000ULL) ? ~u : (u | 0x8000000000000000ULL);
}
__device__ __forceinline__ double decd(ull u){
  ull v = (u & 0x8000000000000000ULL) ? (u & 0x7FFFFFFFFFFFFFFFULL) : ~u;
  return __longlong_as_double((long long)v);
}
__device__ __forceinline__ double lrelu(double z){ return z > 0.0 ? z : 0.2*z; }

__global__ void zeroi_k(int* __restrict__ p, int n){
  int t = blockIdx.x*blockDim.x + threadIdx.x;
  if (t < n) p[t] = 0;
}

// ---------------- GEMM: Out[n,256] = A[n,256] @ W[256,256], f64 accumulate ----------------
template<typename TA>
__global__ __launch_bounds__(256) void gemm_k(const TA* __restrict__ A, const float* __restrict__ W,
                                              double* __restrict__ Out, int n){
  __shared__ double As[16][65];
  __shared__ double Bs[16][65];
  const int tid = threadIdx.x;
  const int r0 = blockIdx.x*64, c0 = blockIdx.y*64;
  const int ty = tid>>4, tx = tid&15;
  double acc[4][4] = {};
  for (int k0 = 0; k0 < 256; k0 += 16){
    int kA = tid & 15;
    #pragma unroll
    for (int i=0;i<4;i++){
      int rr = (tid>>4) + i*16;
      int gr = r0 + rr;
      As[kA][rr] = (gr < n) ? (double)A[(long)gr*256 + k0 + kA] : 0.0;
    }
    int cB = tid & 63;
    #pragma unroll
    for (int i=0;i<4;i++){
      int kk = (tid>>6) + i*4;
      Bs[kk][cB] = (double)W[(k0+kk)*256 + c0 + cB];
    }
    __syncthreads();
    #pragma unroll
    for (int k=0;k<16;k++){
      double a[4], b[4];
      #pragma unroll
      for (int i=0;i<4;i++) a[i] = As[k][ty*4+i];
      #pragma unroll
      for (int j=0;j<4;j++) b[j] = Bs[k][tx*4+j];
      #pragma unroll
      for (int i=0;i<4;i++)
        #pragma unroll
        for (int j=0;j<4;j++)
          acc[i][j] = fma(a[i], b[j], acc[i][j]);
    }
    __syncthreads();
  }
  #pragma unroll
  for (int i=0;i<4;i++){
    int gr = r0 + ty*4 + i;
    if (gr < n){
      #pragma unroll
      for (int j=0;j<4;j++)
        Out[(long)gr*256 + c0 + tx*4 + j] = acc[i][j];
    }
  }
}

// ---------------- attention coefficients ----------------
__global__ void attn_k(const double* __restrict__ Hh, const float* __restrict__ asrc,
                       const float* __restrict__ adst, double* __restrict__ als,
                       double* __restrict__ ald){
  int i = blockIdx.x; int ch = threadIdx.x; int head = ch>>6; int lane = ch&63;
  double hv = Hh[(long)i*256 + ch];
  double vs = hv * (double)asrc[ch];
  double vd = hv * (double)adst[ch];
  for (int off=32; off; off>>=1){ vs += __shfl_down(vs, off); vd += __shfl_down(vd, off); }
  if (lane == 0){ als[i*4+head] = vs; ald[i*4+head] = vd; }
}

__global__ void initm_k(const double* __restrict__ als, const double* __restrict__ ald,
                        ull* __restrict__ menc, int total){
  int t = blockIdx.x*blockDim.x + threadIdx.x;
  if (t >= total) return;
  menc[t] = encd(lrelu(als[t] + ald[t]));
}

__global__ void edgemax_k(const int* __restrict__ src, const int* __restrict__ dst,
                          const int* __restrict__ msk, const double* __restrict__ als,
                          const double* __restrict__ ald, ull* __restrict__ menc, int e){
  int t = blockIdx.x*blockDim.x + threadIdx.x;
  if (t >= e) return;
  if (msk && !msk[t]) return;
  int s = src[t], d = dst[t];
  #pragma unroll
  for (int h=0;h<4;h++){
    double ev = lrelu(als[s*4+h] + ald[d*4+h]);
    atomicMax(&menc[d*4+h], encd(ev));
  }
}

__global__ void wself_k(const double* __restrict__ als, const double* __restrict__ ald,
                        const ull* __restrict__ menc, double* __restrict__ wself, int total){
  int t = blockIdx.x*blockDim.x + threadIdx.x;
  if (t >= total) return;
  double e = lrelu(als[t] + ald[t]);
  wself[t] = exp(e - decd(menc[t]));
}

__global__ void edgew_k(const int* __restrict__ src, const int* __restrict__ dst,
                        const int* __restrict__ msk, const double* __restrict__ als,
                        const double* __restrict__ ald, const ull* __restrict__ menc,
                        double* __restrict__ wedge, int e){
  int t = blockIdx.x*blockDim.x + threadIdx.x;
  if (t >= e) return;
  int s = src[t], d = dst[t];
  bool ok = (!msk) || (msk[t] != 0);
  #pragma unroll
  for (int h=0;h<4;h++){
    double w = 0.0;
    if (ok){
      double ev = lrelu(als[s*4+h] + ald[d*4+h]);
      w = exp(ev - decd(menc[d*4+h]));
    }
    wedge[(long)t*4+h] = w;
  }
}

__global__ void deg_k(const int* __restrict__ dst, const int* __restrict__ msk,
                      int* __restrict__ deg, int e){
  int t = blockIdx.x*blockDim.x + threadIdx.x;
  if (t >= e) return;
  if (msk && !msk[t]) return;
  atomicAdd(&deg[dst[t]], 1);
}

__global__ __launch_bounds__(1024) void scan_k(const int* __restrict__ deg, int* __restrict__ rowptr, int n){
  __shared__ int buf[1024];
  __shared__ int carry;
  int tid = threadIdx.x;
  if (tid == 0){ carry = 0; rowptr[0] = 0; }
  __syncthreads();
  for (int base = 0; base < n; base += 1024){
    int v = (base + tid < n) ? deg[base + tid] : 0;
    buf[tid] = v; __syncthreads();
    for (int off = 1; off < 1024; off <<= 1){
      int t_ = (tid >= off) ? buf[tid - off] : 0;
      __syncthreads();
      buf[tid] += t_;
      __syncthreads();
    }
    if (base + tid < n) rowptr[base + tid + 1] = carry + buf[tid];
    __syncthreads();
    if (tid == 0) carry += buf[1023];
    __syncthreads();
  }
}

__global__ void place_k(const int* __restrict__ dst, const int* __restrict__ msk,
                        const int* __restrict__ rowptr, int* __restrict__ cursor,
                        int* __restrict__ csr, int e){
  int t = blockIdx.x*blockDim.x + threadIdx.x;
  if (t >= e) return;
  if (msk && !msk[t]) return;
  int d = dst[t];
  int slot = atomicAdd(&cursor[d], 1);
  csr[rowptr[d] + slot] = t;
}

// row of X for node i, in registers (one channel per thread); deterministic denominator
__device__ __forceinline__ double gat_row(const double* __restrict__ Hh, const int* __restrict__ srcA,
                                          const int* __restrict__ rowptr, const int* __restrict__ csr,
                                          const double* __restrict__ wed, const double* __restrict__ wse,
                                          const float* __restrict__ bias, int i, int ch, int h){
  double acc = wse[i*4+h] * Hh[(long)i*256 + ch];
  double dsum = wse[i*4+h];
  int b = rowptr[i], e = rowptr[i+1];
  for (int t=b; t<e; t++){
    int eid = csr[t]; int s = srcA[eid];
    double w = wed[(long)eid*4+h];
    acc  = fma(w, Hh[(long)s*256 + ch], acc);
    dsum += w;
  }
  return acc/dsum + (double)bias[ch];
}

__global__ void aggr_score_k(const double* __restrict__ Hh, const int* __restrict__ srcA,
                             const int* __restrict__ rowptr, const int* __restrict__ csr,
                             const double* __restrict__ wed, const double* __restrict__ wse,
                             const float* __restrict__ bias, const float* __restrict__ p,
                             const double* __restrict__ nrm, double* __restrict__ score){
  __shared__ double red[4];
  int i = blockIdx.x, ch = threadIdx.x, h = ch>>6;
  double row = gat_row(Hh, srcA, rowptr, csr, wed, wse, bias, i, ch, h);
  double v = row * (double)p[ch];
  for (int off=32; off; off>>=1) v += __shfl_down(v, off);
  if ((ch&63)==0) red[ch>>6] = v;
  __syncthreads();
  if (ch == 0) score[i] = tanh((red[0]+red[1]+red[2]+red[3]) / nrm[0]);
}

__global__ void aggr_gate_k(const double* __restrict__ Hh, const int* __restrict__ srcA,
                            const int* __restrict__ rowptr, const int* __restrict__ csr,
                            const double* __restrict__ wed, const double* __restrict__ wse,
                            const float* __restrict__ bias, const int* __restrict__ perm,
                            const double* __restrict__ scs, double* __restrict__ Xi){
  int r = blockIdx.x, ch = threadIdx.x, h = ch>>6;
  int i = perm[r];
  double row = gat_row(Hh, srcA, rowptr, csr, wed, wse, bias, i, ch, h);
  double v = row * scs[r];
  Xi[(long)r*256 + ch] = v > 0.0 ? v : 0.0;
}

__global__ void aggr_final_k(const double* __restrict__ Hh, const int* __restrict__ srcA,
                             const int* __restrict__ rowptr, const int* __restrict__ csr,
                             const double* __restrict__ wed, const double* __restrict__ wse,
                             const float* __restrict__ bias, const int* __restrict__ perm,
                             const double* __restrict__ scs, float* __restrict__ out){
  int r = blockIdx.x, ch = threadIdx.x, h = ch>>6;
  int i = perm[r];
  double row = gat_row(Hh, srcA, rowptr, csr, wed, wse, bias, i, ch, h);
  double v = row * scs[r];
  out[(long)r*256 + ch] = (float)(v > 0.0 ? v : 0.0);
}

__global__ void pnorm_k(const float* __restrict__ p, double* __restrict__ norms){
  __shared__ double ws_[4];
  int tid = threadIdx.x;
  double v = (double)p[tid]; v *= v;
  for (int off=32; off; off>>=1) v += __shfl_down(v, off);
  if ((tid&63)==0) ws_[tid>>6] = v;
  __syncthreads();
  if (tid == 0) norms[0] = sqrt(ws_[0]+ws_[1]+ws_[2]+ws_[3]);
}

__global__ void key_k(const double* __restrict__ score, ull* __restrict__ k64,
                      unsigned int* __restrict__ k32, int n){
  int i = blockIdx.x*blockDim.x + threadIdx.x;
  if (i >= n) return;
  ull e = encd(score[i]);
  k64[i] = e; k32[i] = (unsigned int)(e >> 32);
}

// rank[i] = #{j : key_j > key_i or (== and j<i)}
__global__ __launch_bounds__(256) void rank_k(const unsigned int* __restrict__ k32,
                                              const ull* __restrict__ k64,
                                              int* __restrict__ rank, int n, int jchunk){
  __shared__ unsigned int tile[512];
  long ib = (long)blockIdx.x * 1024;
  unsigned int ki[4]; ull kif[4]; int idx[4]; int cnt[4];
  #pragma unroll
  for (int q=0;q<4;q++){
    idx[q] = (int)(ib + q*256 + threadIdx.x);
    bool v = idx[q] < n;
    ki[q]  = v ? k32[idx[q]] : 0xFFFFFFFFu;
    kif[q] = v ? k64[idx[q]] : ~0ULL;
    cnt[q] = 0;
  }
  int jbeg = blockIdx.y * jchunk;
  int jend = min(n, jbeg + jchunk);
  for (int j0 = jbeg; j0 < jend; j0 += 512){
    int lim = min(512, jend - j0);
    for (int t = threadIdx.x; t < 512; t += 256)
      tile[t] = (t < lim) ? k32[j0 + t] : 0u;
    __syncthreads();
    for (int t = 0; t < lim; t++){
      unsigned int kj = tile[t];
      bool anyeq = (kj==ki[0]) | (kj==ki[1]) | (kj==ki[2]) | (kj==ki[3]);
      #pragma unroll
      for (int q=0;q<4;q++) cnt[q] += (kj > ki[q]);
      if (__builtin_expect(anyeq, 0)){
        int j = j0 + t;
        ull kjf = k64[j];
        #pragma unroll
        for (int q=0;q<4;q++)
          if (kj == ki[q])
            cnt[q] += ((kjf > kif[q]) || (kjf == kif[q] && j < idx[q])) ? 1 : 0;
      }
    }
    __syncthreads();
  }
  #pragma unroll
  for (int q=0;q<4;q++) if (idx[q] < n) atomicAdd(&rank[idx[q]], cnt[q]);
}

__global__ void scatter_k(const double* __restrict__ score, const int* __restrict__ rank,
                          int* __restrict__ perm, int* __restrict__ inv,
                          double* __restrict__ scs, int n, int k){
  int i = blockIdx.x*blockDim.x + threadIdx.x;
  if (i >= n) return;
  int r = rank[i];
  inv[i] = (r < k) ? r : -1;
  if (r < k){ perm[r] = i; scs[r] = score[i]; }
}

__global__ void reindex_k(const int* __restrict__ src, const int* __restrict__ dst,
                          const int* __restrict__ inv,
                          int* __restrict__ ns, int* __restrict__ nd, int* __restrict__ nmsk, int e){
  int t = blockIdx.x*blockDim.x + threadIdx.x;
  if (t >= e) return;
  int a = inv[src[t]], b = inv[dst[t]];
  int ok = (a >= 0) && (b >= 0);
  ns[t] = ok ? a : 0; nd[t] = ok ? b : 0; nmsk[t] = ok;
}

__global__ void finedge_k(const int* __restrict__ ns, const int* __restrict__ nd,
                          const int* __restrict__ msk, const int* __restrict__ inv,
                          float* __restrict__ osrc, float* __restrict__ odst,
                          float* __restrict__ omsk, int e){
  int t = blockIdx.x*blockDim.x + threadIdx.x;
  if (t >= e) return;
  int a = inv[ns[t]], b = inv[nd[t]];
  int ok = msk[t] && (a >= 0) && (b >= 0);
  osrc[t] = (float)(ok ? a : 0);
  odst[t] = (float)(ok ? b : 0);
  omsk[t] = ok ? 1.0f : 0.0f;
}

__global__ void zerof_k(float* __restrict__ o, int n){
  int t = blockIdx.x*blockDim.x + threadIdx.x;
  if (t < n) o[t] = 0.0f;
}

extern "C" void kernel_launch(void* const* d_in, const int* in_sizes, int n_in,
                              void* d_out, int out_size, void* d_ws, size_t ws_size,
                              hipStream_t stream){
  (void)in_sizes; (void)n_in; (void)out_size; (void)ws_size;
  const float* x   = (const float*)d_in[0];
  const int*   ei  = (const int*)d_in[1];
  const float* W1  = (const float*)d_in[3];
  const float* as1 = (const float*)d_in[4];
  const float* ad1 = (const float*)d_in[5];
  const float* b1  = (const float*)d_in[6];
  const float* p1  = (const float*)d_in[7];
  const float* W2  = (const float*)d_in[8];
  const float* as2 = (const float*)d_in[9];
  const float* ad2 = (const float*)d_in[10];
  const float* b2  = (const float*)d_in[11];
  const float* p2  = (const float*)d_in[12];
  const int* src0 = ei;
  const int* dst0 = ei + EE;

  char* cur = (char*)d_ws;
  auto take = [&](size_t bytes)->void*{ void* p = (void*)cur; cur += (bytes + 255) & ~(size_t)255; return p; };
  double* bufA = (double*)take((size_t)NN1*256*8);   // Hh1; later Hh2 (first 25000 rows)
  double* Xi   = (double*)take((size_t)KK1*256*8);   // gated pool-1 output (f64)
  double* als  = (double*)take((size_t)NN1*4*8);
  double* ald  = (double*)take((size_t)NN1*4*8);
  ull*    menc = (ull*)   take((size_t)NN1*4*8);
  double* wse  = (double*)take((size_t)NN1*4*8);
  double* wed  = (double*)take((size_t)EE*4*8);
  double* sco  = (double*)take((size_t)NN1*8);
  double* scs  = (double*)take((size_t)KK1*8);
  double* nrm  = (double*)take(256);
  ull*    k64  = (ull*)   take((size_t)NN1*8);
  unsigned int* k32 = (unsigned int*)take((size_t)NN1*4);
  int* rnk  = (int*)take((size_t)NN1*4);
  int* prm  = (int*)take((size_t)KK1*4);
  int* inv  = (int*)take((size_t)NN1*4);
  int* deg  = (int*)take((size_t)(NN1+1)*4);
  int* rwp  = (int*)take((size_t)(NN1+1)*4);
  int* cursr= (int*)take((size_t)NN1*4);
  int* csr  = (int*)take((size_t)EE*4);
  int* ns   = (int*)take((size_t)EE*4);
  int* nd   = (int*)take((size_t)EE*4);
  int* mk2  = (int*)take((size_t)EE*4);

  double* Hh1 = bufA;
  double* Hh2 = bufA;   // reuse (first 25000 rows) after Hh1 is dead

  float* out = (float*)d_out;
  float* o_x = out;                         // 12500*256
  float* o_s = out + (size_t)KK2*256;       // 600000
  float* o_d = o_s + EE;                    // 600000
  float* o_m = o_d + EE;                    // 600000
  float* o_b = o_m + EE;                    // 12500

  // ---------------- stage 1: GATConv on (N1, E) ----------------
  gemm_k<float><<<dim3(CDIV(NN1,64),4),256,0,stream>>>(x, W1, Hh1, NN1);
  attn_k<<<NN1,256,0,stream>>>(Hh1, as1, ad1, als, ald);
  initm_k<<<CDIV(NN1*4,256),256,0,stream>>>(als, ald, menc, NN1*4);
  edgemax_k<<<CDIV(EE,256),256,0,stream>>>(src0, dst0, nullptr, als, ald, menc, EE);
  wself_k<<<CDIV(NN1*4,256),256,0,stream>>>(als, ald, menc, wse, NN1*4);
  edgew_k<<<CDIV(EE,256),256,0,stream>>>(src0, dst0, nullptr, als, ald, menc, wed, EE);
  zeroi_k<<<CDIV(NN1,256),256,0,stream>>>(deg, NN1);
  zeroi_k<<<CDIV(NN1,256),256,0,stream>>>(cursr, NN1);
  deg_k<<<CDIV(EE,256),256,0,stream>>>(dst0, nullptr, deg, EE);
  scan_k<<<1,1024,0,stream>>>(deg, rwp, NN1);
  place_k<<<CDIV(EE,256),256,0,stream>>>(dst0, nullptr, rwp, cursr, csr, EE);

  // ---------------- pool 1 (score fused into aggregation) ----------------
  pnorm_k<<<1,256,0,stream>>>(p1, nrm);
  aggr_score_k<<<NN1,256,0,stream>>>(Hh1, src0, rwp, csr, wed, wse, b1, p1, nrm, sco);
  key_k<<<CDIV(NN1,256),256,0,stream>>>(sco, k64, k32, NN1);
  zeroi_k<<<CDIV(NN1,256),256,0,stream>>>(rnk, NN1);
  { int jc = ((CDIV(NN1,14)+511)/512)*512;
    rank_k<<<dim3(CDIV(NN1,1024), CDIV(NN1,jc)),256,0,stream>>>(k32, k64, rnk, NN1, jc); }
  scatter_k<<<CDIV(NN1,256),256,0,stream>>>(sco, rnk, prm, inv, scs, NN1, KK1);
  aggr_gate_k<<<KK1,256,0,stream>>>(Hh1, src0, rwp, csr, wed, wse, b1, prm, scs, Xi); // relu inside
  reindex_k<<<CDIV(EE,256),256,0,stream>>>(src0, dst0, inv, ns, nd, mk2, EE);

  // ---------------- stage 2: GATConv on (K1, masked E) ----------------
  gemm_k<double><<<dim3(CDIV(KK1,64),4),256,0,stream>>>(Xi, W2, Hh2, KK1);
  attn_k<<<KK1,256,0,stream>>>(Hh2, as2, ad2, als, ald);
  initm_k<<<CDIV(KK1*4,256),256,0,stream>>>(als, ald, menc, KK1*4);
  edgemax_k<<<CDIV(EE,256),256,0,stream>>>(ns, nd, mk2, als, ald, menc, EE);
  wself_k<<<CDIV(KK1*4,256),256,0,stream>>>(als, ald, menc, wse, KK1*4);
  edgew_k<<<CDIV(EE,256),256,0,stream>>>(ns, nd, mk2, als, ald, menc, wed, EE);
  zeroi_k<<<CDIV(KK1,256),256,0,stream>>>(deg, KK1);
  zeroi_k<<<CDIV(KK1,256),256,0,stream>>>(cursr, KK1);
  deg_k<<<CDIV(EE,256),256,0,stream>>>(nd, mk2, deg, EE);
  scan_k<<<1,1024,0,stream>>>(deg, rwp, KK1);
  place_k<<<CDIV(EE,256),256,0,stream>>>(nd, mk2, rwp, cursr, csr, EE);

  // ---------------- pool 2 + outputs ----------------
  pnorm_k<<<1,256,0,stream>>>(p2, nrm);
  aggr_score_k<<<KK1,256,0,stream>>>(Hh2, ns, rwp, csr, wed, wse, b2, p2, nrm, sco);
  key_k<<<CDIV(KK1,256),256,0,stream>>>(sco, k64, k32, KK1);
  zeroi_k<<<CDIV(KK1,256),256,0,stream>>>(rnk, KK1);
  { int jc = ((CDIV(KK1,14)+511)/512)*512;
    rank_k<<<dim3(CDIV(KK1,1024), CDIV(KK1,jc)),256,0,stream>>>(k32, k64, rnk, KK1, jc); }
  scatter_k<<<CDIV(KK1,256),256,0,stream>>>(sco, rnk, prm, inv, scs, KK1, KK2);
  aggr_final_k<<<KK2,256,0,stream>>>(Hh2, ns, rwp, csr, wed, wse, b2, prm, scs, o_x);
  finedge_k<<<CDIV(EE,256),256,0,stream>>>(ns, nd, mk2, inv, o_s, o_d, o_m, EE);
  zerof_k<<<CDIV(KK2,256),256,0,stream>>>(o_b, KK2);
}

// Round 4
// 1539.250 us; speedup vs baseline: 1.4295x; 1.4295x over previous
//
#include <hip/hip_runtime.h>
#include <math.h>

typedef unsigned long long ull;

#define NN1 50000
#define EE  600000
#define KK1 25000
#define KK2 12500

#define NB (1<<18)      // rank buckets
#define BSHIFT 46       // 64-18

#define CDIV(a,b) (((a)+(b)-1)/(b))

__device__ __forceinline__ ull encd(double d){
  ull u = (ull)__double_as_longlong(d);
  return (u & 0x8000000000000000ULL) ? ~u : (u | 0x8000000000000000ULL);
}
__device__ __forceinline__ double decd(ull u){
  ull v = (u & 0x8000000000000000ULL) ? (u & 0x7FFFFFFFFFFFFFFFULL) : ~u;
  return __longlong_as_double((long long)v);
}
__device__ __forceinline__ double lrelu(double z){ return z > 0.0 ? z : 0.2*z; }

__global__ void zeroi_k(int* __restrict__ p, int n){
  int t = blockIdx.x*blockDim.x + threadIdx.x;
  if (t < n) p[t] = 0;
}

// ---------------- GEMM: Out[n,256] = A[n,256] @ W[256,256], f64 accumulate ----------------
template<typename TA>
__global__ __launch_bounds__(256) void gemm_k(const TA* __restrict__ A, const float* __restrict__ W,
                                              double* __restrict__ Out, int n){
  __shared__ double As[16][65];
  __shared__ double Bs[16][65];
  const int tid = threadIdx.x;
  const int r0 = blockIdx.x*64, c0 = blockIdx.y*64;
  const int ty = tid>>4, tx = tid&15;
  double acc[4][4] = {};
  for (int k0 = 0; k0 < 256; k0 += 16){
    int kA = tid & 15;
    #pragma unroll
    for (int i=0;i<4;i++){
      int rr = (tid>>4) + i*16;
      int gr = r0 + rr;
      As[kA][rr] = (gr < n) ? (double)A[(long)gr*256 + k0 + kA] : 0.0;
    }
    int cB = tid & 63;
    #pragma unroll
    for (int i=0;i<4;i++){
      int kk = (tid>>6) + i*4;
      Bs[kk][cB] = (double)W[(k0+kk)*256 + c0 + cB];
    }
    __syncthreads();
    #pragma unroll
    for (int k=0;k<16;k++){
      double a[4], b[4];
      #pragma unroll
      for (int i=0;i<4;i++) a[i] = As[k][ty*4+i];
      #pragma unroll
      for (int j=0;j<4;j++) b[j] = Bs[k][tx*4+j];
      #pragma unroll
      for (int i=0;i<4;i++)
        #pragma unroll
        for (int j=0;j<4;j++)
          acc[i][j] = fma(a[i], b[j], acc[i][j]);
    }
    __syncthreads();
  }
  #pragma unroll
  for (int i=0;i<4;i++){
    int gr = r0 + ty*4 + i;
    if (gr < n){
      #pragma unroll
      for (int j=0;j<4;j++)
        Out[(long)gr*256 + c0 + tx*4 + j] = acc[i][j];
    }
  }
}

// ---------------- attention coefficients ----------------
__global__ void attn_k(const double* __restrict__ Hh, const float* __restrict__ asrc,
                       const float* __restrict__ adst, double* __restrict__ als,
                       double* __restrict__ ald){
  int i = blockIdx.x; int ch = threadIdx.x; int head = ch>>6; int lane = ch&63;
  double hv = Hh[(long)i*256 + ch];
  double vs = hv * (double)asrc[ch];
  double vd = hv * (double)adst[ch];
  for (int off=32; off; off>>=1){ vs += __shfl_down(vs, off); vd += __shfl_down(vd, off); }
  if (lane == 0){ als[i*4+head] = vs; ald[i*4+head] = vd; }
}

__global__ void initm_k(const double* __restrict__ als, const double* __restrict__ ald,
                        ull* __restrict__ menc, int total){
  int t = blockIdx.x*blockDim.x + threadIdx.x;
  if (t >= total) return;
  menc[t] = encd(lrelu(als[t] + ald[t]));
}

__global__ void edgemax_k(const int* __restrict__ src, const int* __restrict__ dst,
                          const int* __restrict__ msk, const double* __restrict__ als,
                          const double* __restrict__ ald, ull* __restrict__ menc, int e){
  int t = blockIdx.x*blockDim.x + threadIdx.x;
  if (t >= e) return;
  if (msk && !msk[t]) return;
  int s = src[t], d = dst[t];
  #pragma unroll
  for (int h=0;h<4;h++){
    double ev = lrelu(als[s*4+h] + ald[d*4+h]);
    atomicMax(&menc[d*4+h], encd(ev));
  }
}

__global__ void wself_k(const double* __restrict__ als, const double* __restrict__ ald,
                        const ull* __restrict__ menc, double* __restrict__ wself, int total){
  int t = blockIdx.x*blockDim.x + threadIdx.x;
  if (t >= total) return;
  double e = lrelu(als[t] + ald[t]);
  wself[t] = exp(e - decd(menc[t]));
}

__global__ void edgew_k(const int* __restrict__ src, const int* __restrict__ dst,
                        const int* __restrict__ msk, const double* __restrict__ als,
                        const double* __restrict__ ald, const ull* __restrict__ menc,
                        double* __restrict__ wedge, int e){
  int t = blockIdx.x*blockDim.x + threadIdx.x;
  if (t >= e) return;
  int s = src[t], d = dst[t];
  bool ok = (!msk) || (msk[t] != 0);
  #pragma unroll
  for (int h=0;h<4;h++){
    double w = 0.0;
    if (ok){
      double ev = lrelu(als[s*4+h] + ald[d*4+h]);
      w = exp(ev - decd(menc[d*4+h]));
    }
    wedge[(long)t*4+h] = w;
  }
}

__global__ void deg_k(const int* __restrict__ dst, const int* __restrict__ msk,
                      int* __restrict__ deg, int e){
  int t = blockIdx.x*blockDim.x + threadIdx.x;
  if (t >= e) return;
  if (msk && !msk[t]) return;
  atomicAdd(&deg[dst[t]], 1);
}

// ---------------- hierarchical scan (blocks of 256) ----------------
__global__ __launch_bounds__(256) void scanA_k(int* __restrict__ a, int* __restrict__ btot, int n){
  __shared__ int s[256];
  int g = blockIdx.x*256 + threadIdx.x;
  s[threadIdx.x] = (g < n) ? a[g] : 0;
  __syncthreads();
  for (int off=1; off<256; off<<=1){
    int t = (threadIdx.x >= off) ? s[threadIdx.x-off] : 0;
    __syncthreads();
    s[threadIdx.x] += t;
    __syncthreads();
  }
  if (g < n) a[g] = s[threadIdx.x];
  if (threadIdx.x == 255) btot[blockIdx.x] = s[255];
}

__global__ __launch_bounds__(1024) void scanB_k(int* __restrict__ btot, int nb){
  __shared__ int s[1024];
  int t = threadIdx.x;
  s[t] = (t < nb) ? btot[t] : 0;
  __syncthreads();
  for (int off=1; off<1024; off<<=1){
    int v = (t >= off) ? s[t-off] : 0;
    __syncthreads();
    s[t] += v;
    __syncthreads();
  }
  if (t < nb) btot[t] = s[t];
}

__global__ void scanC_rowptr_k(const int* __restrict__ a, const int* __restrict__ btot,
                               int* __restrict__ rowptr, int n){
  int g = blockIdx.x*blockDim.x + threadIdx.x;
  if (g >= n) return;
  int B = g >> 8;
  int off = (B > 0) ? btot[B-1] : 0;
  rowptr[g+1] = a[g] + off;
  if (g == 0) rowptr[0] = 0;
}

__global__ void scanC_above_k(const int* __restrict__ a, const int* __restrict__ btot,
                              int* __restrict__ habove, int nelems, int nbins){
  int g = blockIdx.x*blockDim.x + threadIdx.x;
  if (g >= nbins) return;
  int B = g >> 8;
  int off = (B > 0) ? btot[B-1] : 0;
  habove[g] = nelems - (a[g] + off);
}

__global__ void place_k(const int* __restrict__ dst, const int* __restrict__ msk,
                        const int* __restrict__ rowptr, int* __restrict__ cursor,
                        int* __restrict__ csr, int e){
  int t = blockIdx.x*blockDim.x + threadIdx.x;
  if (t >= e) return;
  if (msk && !msk[t]) return;
  int d = dst[t];
  int slot = atomicAdd(&cursor[d], 1);
  csr[rowptr[d] + slot] = t;
}

// row of X for node i, in registers (one channel per thread); deterministic denominator
__device__ __forceinline__ double gat_row(const double* __restrict__ Hh, const int* __restrict__ srcA,
                                          const int* __restrict__ rowptr, const int* __restrict__ csr,
                                          const double* __restrict__ wed, const double* __restrict__ wse,
                                          const float* __restrict__ bias, int i, int ch, int h){
  double acc = wse[i*4+h] * Hh[(long)i*256 + ch];
  double dsum = wse[i*4+h];
  int b = rowptr[i], e = rowptr[i+1];
  for (int t=b; t<e; t++){
    int eid = csr[t]; int s = srcA[eid];
    double w = wed[(long)eid*4+h];
    acc  = fma(w, Hh[(long)s*256 + ch], acc);
    dsum += w;
  }
  return acc/dsum + (double)bias[ch];
}

// outputs PRE-tanh z (tanh is monotone; ranking by z == ranking by tanh(z))
__global__ void aggr_score_k(const double* __restrict__ Hh, const int* __restrict__ srcA,
                             const int* __restrict__ rowptr, const int* __restrict__ csr,
                             const double* __restrict__ wed, const double* __restrict__ wse,
                             const float* __restrict__ bias, const float* __restrict__ p,
                             const double* __restrict__ nrm, double* __restrict__ z){
  __shared__ double red[4];
  int i = blockIdx.x, ch = threadIdx.x, h = ch>>6;
  double row = gat_row(Hh, srcA, rowptr, csr, wed, wse, bias, i, ch, h);
  double v = row * (double)p[ch];
  for (int off=32; off; off>>=1) v += __shfl_down(v, off);
  if ((ch&63)==0) red[ch>>6] = v;
  __syncthreads();
  if (ch == 0) z[i] = (red[0]+red[1]+red[2]+red[3]) / nrm[0];
}

__global__ void aggr_gate_k(const double* __restrict__ Hh, const int* __restrict__ srcA,
                            const int* __restrict__ rowptr, const int* __restrict__ csr,
                            const double* __restrict__ wed, const double* __restrict__ wse,
                            const float* __restrict__ bias, const int* __restrict__ perm,
                            const double* __restrict__ scs, double* __restrict__ Xi){
  int r = blockIdx.x, ch = threadIdx.x, h = ch>>6;
  int i = perm[r];
  double row = gat_row(Hh, srcA, rowptr, csr, wed, wse, bias, i, ch, h);
  double v = row * scs[r];
  Xi[(long)r*256 + ch] = v > 0.0 ? v : 0.0;
}

__global__ void aggr_final_k(const double* __restrict__ Hh, const int* __restrict__ srcA,
                             const int* __restrict__ rowptr, const int* __restrict__ csr,
                             const double* __restrict__ wed, const double* __restrict__ wse,
                             const float* __restrict__ bias, const int* __restrict__ perm,
                             const double* __restrict__ scs, float* __restrict__ out){
  int r = blockIdx.x, ch = threadIdx.x, h = ch>>6;
  int i = perm[r];
  double row = gat_row(Hh, srcA, rowptr, csr, wed, wse, bias, i, ch, h);
  double v = row * scs[r];
  out[(long)r*256 + ch] = (float)(v > 0.0 ? v : 0.0);
}

__global__ void pnorm_k(const float* __restrict__ p, double* __restrict__ norms){
  __shared__ double ws_[4];
  int tid = threadIdx.x;
  double v = (double)p[tid]; v *= v;
  for (int off=32; off; off>>=1) v += __shfl_down(v, off);
  if ((tid&63)==0) ws_[tid>>6] = v;
  __syncthreads();
  if (tid == 0) norms[0] = sqrt(ws_[0]+ws_[1]+ws_[2]+ws_[3]);
}

// ---------------- bucket-based exact ranking ----------------
__global__ void keyhist_k(const double* __restrict__ z, ull* __restrict__ k64,
                          int* __restrict__ hist, int n){
  int i = blockIdx.x*blockDim.x + threadIdx.x;
  if (i >= n) return;
  ull e = encd(z[i]);
  k64[i] = e;
  atomicAdd(&hist[(int)(e >> BSHIFT)], 1);
}

__global__ void bplace_k(const ull* __restrict__ k64, const int* __restrict__ habove,
                         int* __restrict__ cur, int* __restrict__ isort, int n){
  int i = blockIdx.x*blockDim.x + threadIdx.x;
  if (i >= n) return;
  int b = (int)(k64[i] >> BSHIFT);
  int slot = atomicAdd(&cur[b], 1);
  isort[habove[b] + slot] = i;
}

// rank[i] = #higher-bucket elems + #same-bucket elems with (key>,or ==key && j<i)
__global__ void brank_k(const ull* __restrict__ k64, const int* __restrict__ habove,
                        const int* __restrict__ isort, int* __restrict__ rank, int n){
  int i = blockIdx.x*blockDim.x + threadIdx.x;
  if (i >= n) return;
  ull ki = k64[i];
  int b = (int)(ki >> BSHIFT);
  int lo = habove[b];
  int hi = (b > 0) ? habove[b-1] : n;
  int cnt = 0;
  for (int t = lo; t < hi; t++){
    int j = isort[t];
    ull kj = k64[j];
    cnt += ((kj > ki) || (kj == ki && j < i)) ? 1 : 0;
  }
  rank[i] = lo + cnt;
}

__global__ void scatter_k(const double* __restrict__ z, const int* __restrict__ rank,
                          int* __restrict__ perm, int* __restrict__ inv,
                          double* __restrict__ scs, int n, int k){
  int i = blockIdx.x*blockDim.x + threadIdx.x;
  if (i >= n) return;
  int r = rank[i];
  inv[i] = (r < k) ? r : -1;
  if (r < k){ perm[r] = i; scs[r] = tanh(z[i]); }
}

__global__ void reindex_k(const int* __restrict__ src, const int* __restrict__ dst,
                          const int* __restrict__ inv,
                          int* __restrict__ ns, int* __restrict__ nd, int* __restrict__ nmsk, int e){
  int t = blockIdx.x*blockDim.x + threadIdx.x;
  if (t >= e) return;
  int a = inv[src[t]], b = inv[dst[t]];
  int ok = (a >= 0) && (b >= 0);
  ns[t] = ok ? a : 0; nd[t] = ok ? b : 0; nmsk[t] = ok;
}

__global__ void finedge_k(const int* __restrict__ ns, const int* __restrict__ nd,
                          const int* __restrict__ msk, const int* __restrict__ inv,
                          float* __restrict__ osrc, float* __restrict__ odst,
                          float* __restrict__ omsk, int e){
  int t = blockIdx.x*blockDim.x + threadIdx.x;
  if (t >= e) return;
  int a = inv[ns[t]], b = inv[nd[t]];
  int ok = msk[t] && (a >= 0) && (b >= 0);
  osrc[t] = (float)(ok ? a : 0);
  odst[t] = (float)(ok ? b : 0);
  omsk[t] = ok ? 1.0f : 0.0f;
}

__global__ void zerof_k(float* __restrict__ o, int n){
  int t = blockIdx.x*blockDim.x + threadIdx.x;
  if (t < n) o[t] = 0.0f;
}

extern "C" void kernel_launch(void* const* d_in, const int* in_sizes, int n_in,
                              void* d_out, int out_size, void* d_ws, size_t ws_size,
                              hipStream_t stream){
  (void)in_sizes; (void)n_in; (void)out_size; (void)ws_size;
  const float* x   = (const float*)d_in[0];
  const int*   ei  = (const int*)d_in[1];
  const float* W1  = (const float*)d_in[3];
  const float* as1 = (const float*)d_in[4];
  const float* ad1 = (const float*)d_in[5];
  const float* b1  = (const float*)d_in[6];
  const float* p1  = (const float*)d_in[7];
  const float* W2  = (const float*)d_in[8];
  const float* as2 = (const float*)d_in[9];
  const float* ad2 = (const float*)d_in[10];
  const float* b2  = (const float*)d_in[11];
  const float* p2  = (const float*)d_in[12];
  const int* src0 = ei;
  const int* dst0 = ei + EE;

  char* cur_ = (char*)d_ws;
  auto take = [&](size_t bytes)->void*{ void* p = (void*)cur_; cur_ += (bytes + 255) & ~(size_t)255; return p; };
  double* bufA = (double*)take((size_t)NN1*256*8);   // Hh1; later Hh2
  double* Xi   = (double*)take((size_t)KK1*256*8);
  double* als  = (double*)take((size_t)NN1*4*8);     // aliased by hist during pooling
  double* ald  = (double*)take((size_t)NN1*4*8);     // aliased by habove
  ull*    menc = (ull*)   take((size_t)NN1*4*8);     // aliased by bcur
  double* wse  = (double*)take((size_t)NN1*4*8);
  double* wed  = (double*)take((size_t)EE*4*8);
  double* sco  = (double*)take((size_t)NN1*8);
  double* scs  = (double*)take((size_t)KK1*8);
  double* nrm  = (double*)take(256);
  ull*    k64  = (ull*)   take((size_t)NN1*8);
  int* isort= (int*)take((size_t)NN1*4);
  int* rnk  = (int*)take((size_t)NN1*4);
  int* prm  = (int*)take((size_t)KK1*4);
  int* inv  = (int*)take((size_t)NN1*4);
  int* deg  = (int*)take((size_t)(NN1+1)*4);
  int* rwp  = (int*)take((size_t)(NN1+1)*4);
  int* cursr= (int*)take((size_t)NN1*4);
  int* csr  = (int*)take((size_t)EE*4);
  int* ns   = (int*)take((size_t)EE*4);
  int* nd   = (int*)take((size_t)EE*4);
  int* mk2  = (int*)take((size_t)EE*4);
  int* btot = (int*)take((size_t)1024*4);

  // bucket-rank arrays alias als/ald/menc (dead between edgew and next attn_k)
  int* hist   = (int*)als;    // NB ints = 1 MB <= 1.6 MB
  int* habove = (int*)ald;
  int* bcur   = (int*)menc;

  double* Hh1 = bufA;
  double* Hh2 = bufA;

  float* out = (float*)d_out;
  float* o_x = out;
  float* o_s = out + (size_t)KK2*256;
  float* o_d = o_s + EE;
  float* o_m = o_d + EE;
  float* o_b = o_m + EE;

  // ---------------- stage 1: GATConv on (N1, E) ----------------
  gemm_k<float><<<dim3(CDIV(NN1,64),4),256,0,stream>>>(x, W1, Hh1, NN1);
  attn_k<<<NN1,256,0,stream>>>(Hh1, as1, ad1, als, ald);
  initm_k<<<CDIV(NN1*4,256),256,0,stream>>>(als, ald, menc, NN1*4);
  edgemax_k<<<CDIV(EE,256),256,0,stream>>>(src0, dst0, nullptr, als, ald, menc, EE);
  wself_k<<<CDIV(NN1*4,256),256,0,stream>>>(als, ald, menc, wse, NN1*4);
  edgew_k<<<CDIV(EE,256),256,0,stream>>>(src0, dst0, nullptr, als, ald, menc, wed, EE);
  zeroi_k<<<CDIV(NN1,256),256,0,stream>>>(deg, NN1);
  zeroi_k<<<CDIV(NN1,256),256,0,stream>>>(cursr, NN1);
  deg_k<<<CDIV(EE,256),256,0,stream>>>(dst0, nullptr, deg, EE);
  scanA_k<<<CDIV(NN1,256),256,0,stream>>>(deg, btot, NN1);
  scanB_k<<<1,1024,0,stream>>>(btot, CDIV(NN1,256));
  scanC_rowptr_k<<<CDIV(NN1,256),256,0,stream>>>(deg, btot, rwp, NN1);
  place_k<<<CDIV(EE,256),256,0,stream>>>(dst0, nullptr, rwp, cursr, csr, EE);

  // ---------------- pool 1 ----------------
  pnorm_k<<<1,256,0,stream>>>(p1, nrm);
  aggr_score_k<<<NN1,256,0,stream>>>(Hh1, src0, rwp, csr, wed, wse, b1, p1, nrm, sco);
  zeroi_k<<<NB/256,256,0,stream>>>(hist, NB);
  zeroi_k<<<NB/256,256,0,stream>>>(bcur, NB);
  keyhist_k<<<CDIV(NN1,256),256,0,stream>>>(sco, k64, hist, NN1);
  scanA_k<<<NB/256,256,0,stream>>>(hist, btot, NB);
  scanB_k<<<1,1024,0,stream>>>(btot, NB/256);
  scanC_above_k<<<NB/256,256,0,stream>>>(hist, btot, habove, NN1, NB);
  bplace_k<<<CDIV(NN1,256),256,0,stream>>>(k64, habove, bcur, isort, NN1);
  brank_k<<<CDIV(NN1,256),256,0,stream>>>(k64, habove, isort, rnk, NN1);
  scatter_k<<<CDIV(NN1,256),256,0,stream>>>(sco, rnk, prm, inv, scs, NN1, KK1);
  aggr_gate_k<<<KK1,256,0,stream>>>(Hh1, src0, rwp, csr, wed, wse, b1, prm, scs, Xi);
  reindex_k<<<CDIV(EE,256),256,0,stream>>>(src0, dst0, inv, ns, nd, mk2, EE);

  // ---------------- stage 2: GATConv on (K1, masked E) ----------------
  gemm_k<double><<<dim3(CDIV(KK1,64),4),256,0,stream>>>(Xi, W2, Hh2, KK1);
  attn_k<<<KK1,256,0,stream>>>(Hh2, as2, ad2, als, ald);
  initm_k<<<CDIV(KK1*4,256),256,0,stream>>>(als, ald, menc, KK1*4);
  edgemax_k<<<CDIV(EE,256),256,0,stream>>>(ns, nd, mk2, als, ald, menc, EE);
  wself_k<<<CDIV(KK1*4,256),256,0,stream>>>(als, ald, menc, wse, KK1*4);
  edgew_k<<<CDIV(EE,256),256,0,stream>>>(ns, nd, mk2, als, ald, menc, wed, EE);
  zeroi_k<<<CDIV(KK1,256),256,0,stream>>>(deg, KK1);
  zeroi_k<<<CDIV(KK1,256),256,0,stream>>>(cursr, KK1);
  deg_k<<<CDIV(EE,256),256,0,stream>>>(nd, mk2, deg, EE);
  scanA_k<<<CDIV(KK1,256),256,0,stream>>>(deg, btot, KK1);
  scanB_k<<<1,1024,0,stream>>>(btot, CDIV(KK1,256));
  scanC_rowptr_k<<<CDIV(KK1,256),256,0,stream>>>(deg, btot, rwp, KK1);
  place_k<<<CDIV(EE,256),256,0,stream>>>(nd, mk2, rwp, cursr, csr, EE);

  // ---------------- pool 2 + outputs ----------------
  pnorm_k<<<1,256,0,stream>>>(p2, nrm);
  aggr_score_k<<<KK1,256,0,stream>>>(Hh2, ns, rwp, csr, wed, wse, b2, p2, nrm, sco);
  zeroi_k<<<NB/256,256,0,stream>>>(hist, NB);
  zeroi_k<<<NB/256,256,0,stream>>>(bcur, NB);
  keyhist_k<<<CDIV(KK1,256),256,0,stream>>>(sco, k64, hist, KK1);
  scanA_k<<<NB/256,256,0,stream>>>(hist, btot, NB);
  scanB_k<<<1,1024,0,stream>>>(btot, NB/256);
  scanC_above_k<<<NB/256,256,0,stream>>>(hist, btot, habove, KK1, NB);
  bplace_k<<<CDIV(KK1,256),256,0,stream>>>(k64, habove, bcur, isort, KK1);
  brank_k<<<CDIV(KK1,256),256,0,stream>>>(k64, habove, isort, rnk, KK1);
  scatter_k<<<CDIV(KK1,256),256,0,stream>>>(sco, rnk, prm, inv, scs, KK1, KK2);
  aggr_final_k<<<KK2,256,0,stream>>>(Hh2, ns, rwp, csr, wed, wse, b2, prm, scs, o_x);
  finedge_k<<<CDIV(EE,256),256,0,stream>>>(ns, nd, mk2, inv, o_s, o_d, o_m, EE);
  zerof_k<<<CDIV(KK2,256),256,0,stream>>>(o_b, KK2);
}

// Round 5
// 1100.479 us; speedup vs baseline: 1.9995x; 1.3987x over previous
//
#include <hip/hip_runtime.h>
#include <math.h>

typedef unsigned long long ull;

#define NN1 50000
#define EE  600000
#define KK1 25000
#define KK2 12500

#define NB (1<<18)      // rank buckets
#define BSHIFT 46       // 64-18

#define CDIV(a,b) (((a)+(b)-1)/(b))

__device__ __forceinline__ ull encd(double d){
  ull u = (ull)__double_as_longlong(d);
  return (u & 0x8000000000000000ULL) ? ~u : (u | 0x8000000000000000ULL);
}
__device__ __forceinline__ double decd(ull u){
  ull v = (u & 0x8000000000000000ULL) ? (u & 0x7FFFFFFFFFFFFFFFULL) : ~u;
  return __longlong_as_double((long long)v);
}
__device__ __forceinline__ double lrelu(double z){ return z > 0.0 ? z : 0.2*z; }

__global__ void zeroi_k(int* __restrict__ p, int n){
  int t = blockIdx.x*blockDim.x + threadIdx.x;
  if (t < n) p[t] = 0;
}

// ---------------- GEMM: Out[n,256] = A[n,256] @ W[256,256], f64 math ----------------
// TS = LDS storage type for A (float when A is f32: exact; double for stage-2).
// LDS padded to 65 -> worst 2-way bank aliasing (free on CDNA4).
template<typename TA, typename TS>
__global__ __launch_bounds__(256) void gemm_k(const TA* __restrict__ A, const float* __restrict__ W,
                                              double* __restrict__ Out, int n){
  __shared__ TS    As[32][65];
  __shared__ float Bs[32][65];
  const int tid = threadIdx.x;
  const int r0 = blockIdx.x*64, c0 = blockIdx.y*64;
  const int ty = tid>>4, tx = tid&15;
  double acc[4][4] = {};
  for (int k0 = 0; k0 < 256; k0 += 32){
    int kA = tid & 31, rA = tid >> 5;          // coalesced global A reads
    #pragma unroll
    for (int i=0;i<8;i++){
      int rr = rA + i*8;
      int gr = r0 + rr;
      As[kA][rr] = (gr < n) ? (TS)A[(long)gr*256 + k0 + kA] : (TS)0;
    }
    int cB = tid & 63, kB = tid >> 6;          // coalesced global W reads
    #pragma unroll
    for (int i=0;i<8;i++){
      int kk = kB + i*4;
      Bs[kk][cB] = W[(k0+kk)*256 + c0 + cB];
    }
    __syncthreads();
    #pragma unroll
    for (int k=0;k<32;k++){
      double a[4], b[4];
      #pragma unroll
      for (int i=0;i<4;i++) a[i] = (double)As[k][ty*4+i];
      #pragma unroll
      for (int j=0;j<4;j++) b[j] = (double)Bs[k][tx*4+j];
      #pragma unroll
      for (int i=0;i<4;i++)
        #pragma unroll
        for (int j=0;j<4;j++)
          acc[i][j] = fma(a[i], b[j], acc[i][j]);
    }
    __syncthreads();
  }
  #pragma unroll
  for (int i=0;i<4;i++){
    int gr = r0 + ty*4 + i;
    if (gr < n){
      #pragma unroll
      for (int j=0;j<4;j++)
        Out[(long)gr*256 + c0 + tx*4 + j] = acc[i][j];
    }
  }
}

// ---------------- attention coefficients + score projection hp = h . p ----------------
__global__ void attn_k(const double* __restrict__ Hh, const float* __restrict__ asrc,
                       const float* __restrict__ adst, const float* __restrict__ p,
                       double* __restrict__ als, double* __restrict__ ald,
                       double* __restrict__ hp){
  int i = blockIdx.x; int ch = threadIdx.x; int head = ch>>6; int lane = ch&63;
  double hv = Hh[(long)i*256 + ch];
  double vs = hv * (double)asrc[ch];
  double vd = hv * (double)adst[ch];
  double vp = hv * (double)p[ch];
  for (int off=32; off; off>>=1){
    vs += __shfl_down(vs, off); vd += __shfl_down(vd, off); vp += __shfl_down(vp, off);
  }
  if (lane == 0){ als[i*4+head] = vs; ald[i*4+head] = vd; hp[i*4+head] = vp; }
}

__global__ void initm_k(const double* __restrict__ als, const double* __restrict__ ald,
                        ull* __restrict__ menc, int total){
  int t = blockIdx.x*blockDim.x + threadIdx.x;
  if (t >= total) return;
  menc[t] = encd(lrelu(als[t] + ald[t]));
}

// edge max + degree count in one pass
__global__ void edgemax_k(const int* __restrict__ src, const int* __restrict__ dst,
                          const int* __restrict__ msk, const double* __restrict__ als,
                          const double* __restrict__ ald, ull* __restrict__ menc,
                          int* __restrict__ deg, int e){
  int t = blockIdx.x*blockDim.x + threadIdx.x;
  if (t >= e) return;
  if (msk && !msk[t]) return;
  int s = src[t], d = dst[t];
  atomicAdd(&deg[d], 1);
  #pragma unroll
  for (int h=0;h<4;h++){
    double ev = lrelu(als[s*4+h] + ald[d*4+h]);
    atomicMax(&menc[d*4+h], encd(ev));
  }
}

__global__ void wself_k(const double* __restrict__ als, const double* __restrict__ ald,
                        const ull* __restrict__ menc, double* __restrict__ wself, int total){
  int t = blockIdx.x*blockDim.x + threadIdx.x;
  if (t >= total) return;
  double e = lrelu(als[t] + ald[t]);
  wself[t] = exp(e - decd(menc[t]));
}

__global__ void edgew_k(const int* __restrict__ src, const int* __restrict__ dst,
                        const int* __restrict__ msk, const double* __restrict__ als,
                        const double* __restrict__ ald, const ull* __restrict__ menc,
                        double* __restrict__ wedge, int e){
  int t = blockIdx.x*blockDim.x + threadIdx.x;
  if (t >= e) return;
  int s = src[t], d = dst[t];
  bool ok = (!msk) || (msk[t] != 0);
  #pragma unroll
  for (int h=0;h<4;h++){
    double w = 0.0;
    if (ok){
      double ev = lrelu(als[s*4+h] + ald[d*4+h]);
      w = exp(ev - decd(menc[d*4+h]));
    }
    wedge[(long)t*4+h] = w;
  }
}

// ---------------- hierarchical scan (blocks of 256) ----------------
__global__ __launch_bounds__(256) void scanA_k(int* __restrict__ a, int* __restrict__ btot, int n){
  __shared__ int s[256];
  int g = blockIdx.x*256 + threadIdx.x;
  s[threadIdx.x] = (g < n) ? a[g] : 0;
  __syncthreads();
  for (int off=1; off<256; off<<=1){
    int t = (threadIdx.x >= off) ? s[threadIdx.x-off] : 0;
    __syncthreads();
    s[threadIdx.x] += t;
    __syncthreads();
  }
  if (g < n) a[g] = s[threadIdx.x];
  if (threadIdx.x == 255) btot[blockIdx.x] = s[255];
}

__global__ __launch_bounds__(1024) void scanB_k(int* __restrict__ btot, int nb){
  __shared__ int s[1024];
  int t = threadIdx.x;
  s[t] = (t < nb) ? btot[t] : 0;
  __syncthreads();
  for (int off=1; off<1024; off<<=1){
    int v = (t >= off) ? s[t-off] : 0;
    __syncthreads();
    s[t] += v;
    __syncthreads();
  }
  if (t < nb) btot[t] = s[t];
}

__global__ void scanC_rowptr_k(const int* __restrict__ a, const int* __restrict__ btot,
                               int* __restrict__ rowptr, int n){
  int g = blockIdx.x*blockDim.x + threadIdx.x;
  if (g >= n) return;
  int B = g >> 8;
  int off = (B > 0) ? btot[B-1] : 0;
  rowptr[g+1] = a[g] + off;
  if (g == 0) rowptr[0] = 0;
}

__global__ void scanC_above_k(const int* __restrict__ a, const int* __restrict__ btot,
                              int* __restrict__ habove, int nelems, int nbins){
  int g = blockIdx.x*blockDim.x + threadIdx.x;
  if (g >= nbins) return;
  int B = g >> 8;
  int off = (B > 0) ? btot[B-1] : 0;
  habove[g] = nelems - (a[g] + off);
}

__global__ void place_k(const int* __restrict__ dst, const int* __restrict__ msk,
                        const int* __restrict__ rowptr, int* __restrict__ cursor,
                        int* __restrict__ csr, int e){
  int t = blockIdx.x*blockDim.x + threadIdx.x;
  if (t >= e) return;
  if (msk && !msk[t]) return;
  int d = dst[t];
  int slot = atomicAdd(&cursor[d], 1);
  csr[rowptr[d] + slot] = t;
}

// ---------------- score via precomputed hp (8B/edge/head instead of 2KB) ----------------
// thread group of 4 lanes = 4 heads of one node
__global__ void score_csr_k(const double* __restrict__ hp, const double* __restrict__ wed,
                            const double* __restrict__ wse, const int* __restrict__ srcA,
                            const int* __restrict__ rowptr, const int* __restrict__ csr,
                            const double* __restrict__ nrmbp, double* __restrict__ z, int n){
  int g = blockIdx.x*blockDim.x + threadIdx.x;
  int i = g>>2, h = g&3;
  if (i >= n) return;
  double ws = wse[i*4+h];
  double acc = ws * hp[(long)i*4+h];
  double den = ws;
  int b = rowptr[i], e = rowptr[i+1];
  for (int t=b; t<e; t++){
    int eid = csr[t]; int s = srcA[eid];
    double w = wed[(long)eid*4+h];
    acc = fma(w, hp[(long)s*4+h], acc);
    den += w;
  }
  double part = acc/den;
  part += __shfl_xor(part, 1);
  part += __shfl_xor(part, 2);
  if (h == 0) z[i] = (part + nrmbp[1]) / nrmbp[0];
}

// full row of X for node i (one channel per thread); deterministic denominator
__device__ __forceinline__ double gat_row(const double* __restrict__ Hh, const int* __restrict__ srcA,
                                          const int* __restrict__ rowptr, const int* __restrict__ csr,
                                          const double* __restrict__ wed, const double* __restrict__ wse,
                                          const float* __restrict__ bias, int i, int ch, int h){
  double acc = wse[i*4+h] * Hh[(long)i*256 + ch];
  double dsum = wse[i*4+h];
  int b = rowptr[i], e = rowptr[i+1];
  for (int t=b; t<e; t++){
    int eid = csr[t]; int s = srcA[eid];
    double w = wed[(long)eid*4+h];
    acc  = fma(w, Hh[(long)s*256 + ch], acc);
    dsum += w;
  }
  return acc/dsum + (double)bias[ch];
}

__global__ void aggr_gate_k(const double* __restrict__ Hh, const int* __restrict__ srcA,
                            const int* __restrict__ rowptr, const int* __restrict__ csr,
                            const double* __restrict__ wed, const double* __restrict__ wse,
                            const float* __restrict__ bias, const int* __restrict__ perm,
                            const double* __restrict__ scs, double* __restrict__ Xi){
  int r = blockIdx.x, ch = threadIdx.x, h = ch>>6;
  int i = perm[r];
  double row = gat_row(Hh, srcA, rowptr, csr, wed, wse, bias, i, ch, h);
  double v = row * scs[r];
  Xi[(long)r*256 + ch] = v > 0.0 ? v : 0.0;
}

__global__ void aggr_final_k(const double* __restrict__ Hh, const int* __restrict__ srcA,
                             const int* __restrict__ rowptr, const int* __restrict__ csr,
                             const double* __restrict__ wed, const double* __restrict__ wse,
                             const float* __restrict__ bias, const int* __restrict__ perm,
                             const double* __restrict__ scs, float* __restrict__ out){
  int r = blockIdx.x, ch = threadIdx.x, h = ch>>6;
  int i = perm[r];
  double row = gat_row(Hh, srcA, rowptr, csr, wed, wse, bias, i, ch, h);
  double v = row * scs[r];
  out[(long)r*256 + ch] = (float)(v > 0.0 ? v : 0.0);
}

// ||p|| and b.p
__global__ void pnorm_k(const float* __restrict__ p, const float* __restrict__ bias,
                        double* __restrict__ nrmbp){
  __shared__ double ws_[8];
  int tid = threadIdx.x;
  double pv = (double)p[tid];
  double v = pv*pv;
  double w = (double)bias[tid]*pv;
  for (int off=32; off; off>>=1){ v += __shfl_down(v, off); w += __shfl_down(w, off); }
  if ((tid&63)==0){ ws_[tid>>6] = v; ws_[4+(tid>>6)] = w; }
  __syncthreads();
  if (tid == 0){
    nrmbp[0] = sqrt(ws_[0]+ws_[1]+ws_[2]+ws_[3]);
    nrmbp[1] = ws_[4]+ws_[5]+ws_[6]+ws_[7];
  }
}

// ---------------- bucket-based exact ranking ----------------
__global__ void keyhist_k(const double* __restrict__ z, ull* __restrict__ k64,
                          int* __restrict__ hist, int n){
  int i = blockIdx.x*blockDim.x + threadIdx.x;
  if (i >= n) return;
  ull e = encd(z[i]);
  k64[i] = e;
  atomicAdd(&hist[(int)(e >> BSHIFT)], 1);
}

__global__ void bplace_k(const ull* __restrict__ k64, const int* __restrict__ habove,
                         int* __restrict__ cur, int* __restrict__ isort, int n){
  int i = blockIdx.x*blockDim.x + threadIdx.x;
  if (i >= n) return;
  int b = (int)(k64[i] >> BSHIFT);
  int slot = atomicAdd(&cur[b], 1);
  isort[habove[b] + slot] = i;
}

__global__ void brank_k(const ull* __restrict__ k64, const int* __restrict__ habove,
                        const int* __restrict__ isort, int* __restrict__ rank, int n){
  int i = blockIdx.x*blockDim.x + threadIdx.x;
  if (i >= n) return;
  ull ki = k64[i];
  int b = (int)(ki >> BSHIFT);
  int lo = habove[b];
  int hi = (b > 0) ? habove[b-1] : n;
  int cnt = 0;
  for (int t = lo; t < hi; t++){
    int j = isort[t];
    ull kj = k64[j];
    cnt += ((kj > ki) || (kj == ki && j < i)) ? 1 : 0;
  }
  rank[i] = lo + cnt;
}

__global__ void scatter_k(const double* __restrict__ z, const int* __restrict__ rank,
                          int* __restrict__ perm, int* __restrict__ inv,
                          double* __restrict__ scs, int n, int k){
  int i = blockIdx.x*blockDim.x + threadIdx.x;
  if (i >= n) return;
  int r = rank[i];
  inv[i] = (r < k) ? r : -1;
  if (r < k){ perm[r] = i; scs[r] = tanh(z[i]); }
}

__global__ void reindex_k(const int* __restrict__ src, const int* __restrict__ dst,
                          const int* __restrict__ inv,
                          int* __restrict__ ns, int* __restrict__ nd, int* __restrict__ nmsk, int e){
  int t = blockIdx.x*blockDim.x + threadIdx.x;
  if (t >= e) return;
  int a = inv[src[t]], b = inv[dst[t]];
  int ok = (a >= 0) && (b >= 0);
  ns[t] = ok ? a : 0; nd[t] = ok ? b : 0; nmsk[t] = ok;
}

__global__ void finedge_k(const int* __restrict__ ns, const int* __restrict__ nd,
                          const int* __restrict__ msk, const int* __restrict__ inv,
                          float* __restrict__ osrc, float* __restrict__ odst,
                          float* __restrict__ omsk, int e){
  int t = blockIdx.x*blockDim.x + threadIdx.x;
  if (t >= e) return;
  int a = inv[ns[t]], b = inv[nd[t]];
  int ok = msk[t] && (a >= 0) && (b >= 0);
  osrc[t] = (float)(ok ? a : 0);
  odst[t] = (float)(ok ? b : 0);
  omsk[t] = ok ? 1.0f : 0.0f;
}

__global__ void zerof_k(float* __restrict__ o, int n){
  int t = blockIdx.x*blockDim.x + threadIdx.x;
  if (t < n) o[t] = 0.0f;
}

extern "C" void kernel_launch(void* const* d_in, const int* in_sizes, int n_in,
                              void* d_out, int out_size, void* d_ws, size_t ws_size,
                              hipStream_t stream){
  (void)in_sizes; (void)n_in; (void)out_size; (void)ws_size;
  const float* x   = (const float*)d_in[0];
  const int*   ei  = (const int*)d_in[1];
  const float* W1  = (const float*)d_in[3];
  const float* as1 = (const float*)d_in[4];
  const float* ad1 = (const float*)d_in[5];
  const float* b1  = (const float*)d_in[6];
  const float* p1  = (const float*)d_in[7];
  const float* W2  = (const float*)d_in[8];
  const float* as2 = (const float*)d_in[9];
  const float* ad2 = (const float*)d_in[10];
  const float* b2  = (const float*)d_in[11];
  const float* p2  = (const float*)d_in[12];
  const int* src0 = ei;
  const int* dst0 = ei + EE;

  char* cur_ = (char*)d_ws;
  auto take = [&](size_t bytes)->void*{ void* p = (void*)cur_; cur_ += (bytes + 255) & ~(size_t)255; return p; };
  double* bufA = (double*)take((size_t)NN1*256*8);   // Hh1; later Hh2
  double* Xi   = (double*)take((size_t)KK1*256*8);
  double* als  = (double*)take((size_t)NN1*4*8);     // aliased by hist during pooling
  double* ald  = (double*)take((size_t)NN1*4*8);     // aliased by habove
  ull*    menc = (ull*)   take((size_t)NN1*4*8);     // aliased by bcur
  double* wse  = (double*)take((size_t)NN1*4*8);
  double* hp   = (double*)take((size_t)NN1*4*8);
  double* wed  = (double*)take((size_t)EE*4*8);
  double* sco  = (double*)take((size_t)NN1*8);
  double* scs  = (double*)take((size_t)KK1*8);
  double* nrm  = (double*)take(256);
  ull*    k64  = (ull*)   take((size_t)NN1*8);
  int* isort= (int*)take((size_t)NN1*4);
  int* rnk  = (int*)take((size_t)NN1*4);
  int* prm  = (int*)take((size_t)KK1*4);
  int* inv  = (int*)take((size_t)NN1*4);
  int* deg  = (int*)take((size_t)(NN1+1)*4);
  int* rwp  = (int*)take((size_t)(NN1+1)*4);
  int* cursr= (int*)take((size_t)NN1*4);
  int* csr  = (int*)take((size_t)EE*4);
  int* ns   = (int*)take((size_t)EE*4);
  int* nd   = (int*)take((size_t)EE*4);
  int* mk2  = (int*)take((size_t)EE*4);
  int* btot = (int*)take((size_t)1024*4);

  // bucket-rank arrays alias als/ald/menc (dead once wed/wse are built)
  int* hist   = (int*)als;
  int* habove = (int*)ald;
  int* bcur   = (int*)menc;

  double* Hh1 = bufA;
  double* Hh2 = bufA;

  float* out = (float*)d_out;
  float* o_x = out;
  float* o_s = out + (size_t)KK2*256;
  float* o_d = o_s + EE;
  float* o_m = o_d + EE;
  float* o_b = o_m + EE;

  // ---------------- stage 1: GATConv on (N1, E) ----------------
  gemm_k<float,float><<<dim3(CDIV(NN1,64),4),256,0,stream>>>(x, W1, Hh1, NN1);
  attn_k<<<NN1,256,0,stream>>>(Hh1, as1, ad1, p1, als, ald, hp);
  initm_k<<<CDIV(NN1*4,256),256,0,stream>>>(als, ald, menc, NN1*4);
  zeroi_k<<<CDIV(NN1,256),256,0,stream>>>(deg, NN1);
  edgemax_k<<<CDIV(EE,256),256,0,stream>>>(src0, dst0, nullptr, als, ald, menc, deg, EE);
  wself_k<<<CDIV(NN1*4,256),256,0,stream>>>(als, ald, menc, wse, NN1*4);
  edgew_k<<<CDIV(EE,256),256,0,stream>>>(src0, dst0, nullptr, als, ald, menc, wed, EE);
  zeroi_k<<<CDIV(NN1,256),256,0,stream>>>(cursr, NN1);
  scanA_k<<<CDIV(NN1,256),256,0,stream>>>(deg, btot, NN1);
  scanB_k<<<1,1024,0,stream>>>(btot, CDIV(NN1,256));
  scanC_rowptr_k<<<CDIV(NN1,256),256,0,stream>>>(deg, btot, rwp, NN1);
  place_k<<<CDIV(EE,256),256,0,stream>>>(dst0, nullptr, rwp, cursr, csr, EE);

  // ---------------- pool 1 ----------------
  pnorm_k<<<1,256,0,stream>>>(p1, b1, nrm);
  score_csr_k<<<CDIV(NN1*4,256),256,0,stream>>>(hp, wed, wse, src0, rwp, csr, nrm, sco, NN1);
  zeroi_k<<<NB/256,256,0,stream>>>(hist, NB);
  zeroi_k<<<NB/256,256,0,stream>>>(bcur, NB);
  keyhist_k<<<CDIV(NN1,256),256,0,stream>>>(sco, k64, hist, NN1);
  scanA_k<<<NB/256,256,0,stream>>>(hist, btot, NB);
  scanB_k<<<1,1024,0,stream>>>(btot, NB/256);
  scanC_above_k<<<NB/256,256,0,stream>>>(hist, btot, habove, NN1, NB);
  bplace_k<<<CDIV(NN1,256),256,0,stream>>>(k64, habove, bcur, isort, NN1);
  brank_k<<<CDIV(NN1,256),256,0,stream>>>(k64, habove, isort, rnk, NN1);
  scatter_k<<<CDIV(NN1,256),256,0,stream>>>(sco, rnk, prm, inv, scs, NN1, KK1);
  aggr_gate_k<<<KK1,256,0,stream>>>(Hh1, src0, rwp, csr, wed, wse, b1, prm, scs, Xi);
  reindex_k<<<CDIV(EE,256),256,0,stream>>>(src0, dst0, inv, ns, nd, mk2, EE);

  // ---------------- stage 2: GATConv on (K1, masked E) ----------------
  gemm_k<double,double><<<dim3(CDIV(KK1,64),4),256,0,stream>>>(Xi, W2, Hh2, KK1);
  attn_k<<<KK1,256,0,stream>>>(Hh2, as2, ad2, p2, als, ald, hp);
  initm_k<<<CDIV(KK1*4,256),256,0,stream>>>(als, ald, menc, KK1*4);
  zeroi_k<<<CDIV(KK1,256),256,0,stream>>>(deg, KK1);
  edgemax_k<<<CDIV(EE,256),256,0,stream>>>(ns, nd, mk2, als, ald, menc, deg, EE);
  wself_k<<<CDIV(KK1*4,256),256,0,stream>>>(als, ald, menc, wse, KK1*4);
  edgew_k<<<CDIV(EE,256),256,0,stream>>>(ns, nd, mk2, als, ald, menc, wed, EE);
  zeroi_k<<<CDIV(KK1,256),256,0,stream>>>(cursr, KK1);
  scanA_k<<<CDIV(KK1,256),256,0,stream>>>(deg, btot, KK1);
  scanB_k<<<1,1024,0,stream>>>(btot, CDIV(KK1,256));
  scanC_rowptr_k<<<CDIV(KK1,256),256,0,stream>>>(deg, btot, rwp, KK1);
  place_k<<<CDIV(EE,256),256,0,stream>>>(nd, mk2, rwp, cursr, csr, EE);

  // ---------------- pool 2 + outputs ----------------
  pnorm_k<<<1,256,0,stream>>>(p2, b2, nrm);
  score_csr_k<<<CDIV(KK1*4,256),256,0,stream>>>(hp, wed, wse, ns, rwp, csr, nrm, sco, KK1);
  zeroi_k<<<NB/256,256,0,stream>>>(hist, NB);
  zeroi_k<<<NB/256,256,0,stream>>>(bcur, NB);
  keyhist_k<<<CDIV(KK1,256),256,0,stream>>>(sco, k64, hist, KK1);
  scanA_k<<<NB/256,256,0,stream>>>(hist, btot, NB);
  scanB_k<<<1,1024,0,stream>>>(btot, NB/256);
  scanC_above_k<<<NB/256,256,0,stream>>>(hist, btot, habove, KK1, NB);
  bplace_k<<<CDIV(KK1,256),256,0,stream>>>(k64, habove, bcur, isort, KK1);
  brank_k<<<CDIV(KK1,256),256,0,stream>>>(k64, habove, isort, rnk, KK1);
  scatter_k<<<CDIV(KK1,256),256,0,stream>>>(sco, rnk, prm, inv, scs, KK1, KK2);
  aggr_final_k<<<KK2,256,0,stream>>>(Hh2, ns, rwp, csr, wed, wse, b2, prm, scs, o_x);
  finedge_k<<<CDIV(EE,256),256,0,stream>>>(ns, nd, mk2, inv, o_s, o_d, o_m, EE);
  zerof_k<<<CDIV(KK2,256),256,0,stream>>>(o_b, KK2);
}